// Round 10
// baseline (4269.678 us; speedup 1.0000x reference)
//
#include <hip/hip_runtime.h>

#define SEQ_LEN 256
#define SPIKE_STEPS 7
#define BATCH 128
#define IN_DIM 96
#define HIDDEN 512
#define OUT_DIM 2

// d_ws layout (f32 weights): W0T [96*512] | W1T [512*512] | W2T [512*512]
#define W0T_OFF 0
#define W1T_OFF (IN_DIM * HIDDEN)
#define W2T_OFF (W1T_OFF + HIDDEN * HIDDEN)

typedef float f32x4 __attribute__((ext_vector_type(4)));
typedef float f32x2 __attribute__((ext_vector_type(2)));

__global__ void transpose_kernel(const float* __restrict__ in, float* __restrict__ out,
                                 int rows, int cols) {
    int idx = blockIdx.x * blockDim.x + threadIdx.x;
    if (idx < rows * cols) {
        int r = idx / cols, c = idx - r * cols;
        out[c * rows + r] = in[idx];
    }
}

// Packed f32 fma: acc.{lo,hi} += w * m.{lo,hi}. Lowers to v_pk_fma_f32
// (VOP3P) on gfx950 (proven R5/R7). Each half is an independent IEEE RN fma
// => bit-identical to two scalar __fmaf_rn. The two halves belong to
// DIFFERENT steps' accumulator chains => no reordering within any step.
__device__ __forceinline__ void pkfma(f32x2& acc, float w, f32x2 m) {
    const f32x2 wv = {w, w};
    acc = __builtin_elementwise_fma(wv, m, acc);
}

// Union-batched 7-step row sum (R7's measured-best depth-1 pipeline).
// Rank-indexed masks (addresses = loop index, hoistable); act entries read
// 16-at-a-time as int4; weights software-pipelined one 16-group ahead.
// Numerics: per step s, union rows visited in ascending rank order; active
// rows add fma(1,w,acc)=RN(acc+w); inactive rows add fma(0,w,acc)=acc
// exactly (acc never -0: starts +0, +0 + +/-0 = +0 in RN). Pads are
// (row 0, mask 0). => bit-identical to R1/R3/R7 (absmax must be 0.25).
__device__ __forceinline__ void union_sum7(const float* __restrict__ W,
                                           const int* __restrict__ act,
                                           const float (* __restrict__ fmp)[8],
                                           int npad, int col,
                                           f32x2* __restrict__ acc) {
    if (npad <= 0) return;
    const float* Wt = W + col;
    int rows[16];
    float wc[16];
    {
        const int4* av = reinterpret_cast<const int4*>(act);
        int4 a0 = av[0], a1 = av[1], a2 = av[2], a3 = av[3];
        rows[0]=a0.x; rows[1]=a0.y; rows[2]=a0.z; rows[3]=a0.w;
        rows[4]=a1.x; rows[5]=a1.y; rows[6]=a1.z; rows[7]=a1.w;
        rows[8]=a2.x; rows[9]=a2.y; rows[10]=a2.z; rows[11]=a2.w;
        rows[12]=a3.x; rows[13]=a3.y; rows[14]=a3.z; rows[15]=a3.w;
    }
    #pragma unroll
    for (int k = 0; k < 16; ++k) wc[k] = Wt[rows[k] * HIDDEN];

    for (int n = 16; n < npad; n += 16) {
        int nrows[16];
        float wn[16];
        {
            const int4* av = reinterpret_cast<const int4*>(act + n);
            int4 a0 = av[0], a1 = av[1], a2 = av[2], a3 = av[3];
            nrows[0]=a0.x; nrows[1]=a0.y; nrows[2]=a0.z; nrows[3]=a0.w;
            nrows[4]=a1.x; nrows[5]=a1.y; nrows[6]=a1.z; nrows[7]=a1.w;
            nrows[8]=a2.x; nrows[9]=a2.y; nrows[10]=a2.z; nrows[11]=a2.w;
            nrows[12]=a3.x; nrows[13]=a3.y; nrows[14]=a3.z; nrows[15]=a3.w;
        }
        #pragma unroll
        for (int k = 0; k < 16; ++k) wn[k] = Wt[nrows[k] * HIDDEN];

        const int base = n - 16;
        #pragma unroll
        for (int k = 0; k < 16; ++k) {
            f32x4 fa = *reinterpret_cast<const f32x4*>(&fmp[base + k][0]);
            f32x4 fb = *reinterpret_cast<const f32x4*>(&fmp[base + k][4]);
            pkfma(acc[0], wc[k], __builtin_shufflevector(fa, fa, 0, 1));
            pkfma(acc[1], wc[k], __builtin_shufflevector(fa, fa, 2, 3));
            pkfma(acc[2], wc[k], __builtin_shufflevector(fb, fb, 0, 1));
            pkfma(acc[3], wc[k], __builtin_shufflevector(fb, fb, 2, 3));
        }
        #pragma unroll
        for (int k = 0; k < 16; ++k) wc[k] = wn[k];
    }
    const int base = npad - 16;
    #pragma unroll
    for (int k = 0; k < 16; ++k) {
        f32x4 fa = *reinterpret_cast<const f32x4*>(&fmp[base + k][0]);
        f32x4 fb = *reinterpret_cast<const f32x4*>(&fmp[base + k][4]);
        pkfma(acc[0], wc[k], __builtin_shufflevector(fa, fa, 0, 1));
        pkfma(acc[1], wc[k], __builtin_shufflevector(fa, fa, 2, 3));
        pkfma(acc[2], wc[k], __builtin_shufflevector(fb, fb, 0, 1));
        pkfma(acc[3], wc[k], __builtin_shufflevector(fb, fb, 2, 3));
    }
}

// Build the union active list (ascending neuron order) + rank-indexed
// per-row step-mask floats. m7 = this thread's 7 firing bits.
__device__ __forceinline__ int build_union(const unsigned long long (*zm)[8],
                                           int* act, float (*fmp)[8],
                                           int hwid, int hlane, int htid, int m7) {
    unsigned long long um[8];
    #pragma unroll
    for (int q = 0; q < 8; ++q) {
        unsigned long long u = zm[0][q];
        #pragma unroll
        for (int s = 1; s < SPIKE_STEPS; ++s) u |= zm[s][q];
        um[q] = u;
    }
    int pre = 0, total = 0;
    #pragma unroll
    for (int q = 0; q < 8; ++q) {
        int p = __popcll(um[q]);
        total += p;
        if (q < hwid) pre += p;
    }
    if (m7 != 0) {
        int rank = pre + __popcll(um[hwid] & ((1ull << hlane) - 1ull));
        act[rank] = htid;
        f32x4 v0, v4;
        #pragma unroll
        for (int s = 0; s < 4; ++s) v0[s] = ((m7 >> s) & 1) ? 1.0f : 0.0f;
        #pragma unroll
        for (int s = 0; s < 3; ++s) v4[s] = ((m7 >> (4 + s)) & 1) ? 1.0f : 0.0f;
        v4[3] = 0.f;
        *reinterpret_cast<f32x4*>(&fmp[rank][0]) = v0;
        *reinterpret_cast<f32x4*>(&fmp[rank][4]) = v4;
    }
    int npad = (total + 15) & ~15;
    if (htid < npad - total) {
        act[total + htid] = 0;                         // row 0, mask 0 pad
        const f32x4 z = {0.f, 0.f, 0.f, 0.f};
        *reinterpret_cast<f32x4*>(&fmp[total + htid][0]) = z;
        *reinterpret_cast<f32x4*>(&fmp[total + htid][4]) = z;
    }
    return npad;
}

// MERGED-PAIR kernel: one 1024-thread block per batch element.
// Front half (waves 0-7)  = layer0 + layer1 (step it).
// Back  half (waves 8-15) = layer2 + output (step it-1).
// Wave->SIMD round-robin gives each SIMD 2 front + 2 back waves =>
// 4 waves/SIMD (2x the TLP of the two-block version) and the z1-mask
// handoff is an LDS ring (no zbuf stores, no ctr spin, no cross-XCD L2).
// 3 block-wide barriers per iteration; both halves hit them unconditionally.
__launch_bounds__(1024, 1)
__global__ void snn_merged_kernel(const float* __restrict__ x,     // [256,128,96]
                                  const float* __restrict__ Wout,  // [2,512]
                                  const float* __restrict__ betas, // [3]
                                  const float* __restrict__ thrs,  // [3]
                                  const float* __restrict__ W0T,   // [96,512]
                                  const float* __restrict__ W1T,   // [512,512]
                                  const float* __restrict__ W2T,   // [512,512]
                                  float* __restrict__ out)         // [256,128,2]
{
    const int b     = blockIdx.x;
    const int tid   = threadIdx.x;
    const int half  = tid >> 9;        // 0 = front, 1 = back
    const int htid  = tid & 511;       // column / neuron id within half
    const int hlane = htid & 63;
    const int hwid  = htid >> 6;       // 0..7 within half

    __shared__ float xs[2][IN_DIM];
    __shared__ unsigned long long zm0[SPIKE_STEPS][8];     // front z0 ballots
    __shared__ unsigned long long zr[2][SPIKE_STEPS][8];   // z1 ring (depth 2)
    __shared__ int actF[HIDDEN];
    __shared__ int actB[HIDDEN];
    __shared__ __align__(16) float fmpF[HIDDEN][8];
    __shared__ __align__(16) float fmpB[HIDDEN][8];
    __shared__ float red[16];

    // ---- per-thread state ----
    // front:
    float mem0 = 0.f, mem1 = 0.f;
    // back:
    float mem2 = 0.f, a0s = 0.f, a1s = 0.f;
    const float beta0 = betas[0], beta1 = betas[1], beta2 = betas[2];
    const float thr0  = thrs[0],  thr1  = thrs[1],  thr2  = thrs[2];
    const float wo0 = Wout[htid];
    const float wo1 = Wout[HIDDEN + htid];

    if (half == 0 && tid < IN_DIM) xs[0][tid] = x[(0 * BATCH + b) * IN_DIM + tid];
    __syncthreads();                                       // prologue

    for (int it = 0; it <= SEQ_LEN; ++it) {
        const bool frun = (half == 0) && (it < SEQ_LEN);
        const bool brun = (half == 1) && (it >= 1);

        // ---- phase A: front computes z0 ballots for step it ----
        int m7 = 0;
        if (frun) {
            const int cur = it & 1;
            float cur0 = 0.f;
            #pragma unroll 8
            for (int k = 0; k < IN_DIM; ++k)
                cur0 = __fmaf_rn(xs[cur][k], W0T[k * HIDDEN + htid], cur0);
            if (it + 1 < SEQ_LEN && htid < IN_DIM)
                xs[cur ^ 1][htid] = x[((it + 1) * BATCH + b) * IN_DIM + htid];

            #pragma unroll
            for (int s = 0; s < SPIKE_STEPS; ++s) {
                bool reset0 = (mem0 - thr0) > 0.f;
                mem0 = reset0 ? 0.f : __fadd_rn(__fmul_rn(beta0, mem0), cur0);
                bool z0 = (mem0 - thr0) > 0.f;
                m7 |= (int)z0 << s;
                unsigned long long bal = __ballot(z0);
                if (hlane == 0) zm0[s][hwid] = bal;
            }
        } else if (brun) {
            // back: extract this thread's z1 bits from the ring (step it-1)
            const unsigned long long (*zs)[8] = zr[(it - 1) & 1];
            #pragma unroll
            for (int s = 0; s < SPIKE_STEPS; ++s)
                m7 |= (int)((zs[s][hwid] >> hlane) & 1ull) << s;
        }
        __syncthreads();                                   // B1

        // ---- phase B: both halves build their union lists ----
        int npad = 0;
        if (frun)      npad = build_union(zm0,              actF, fmpF, hwid, hlane, htid, m7);
        else if (brun) npad = build_union(zr[(it - 1) & 1], actB, fmpB, hwid, hlane, htid, m7);
        __syncthreads();                                   // B2

        // ---- phase C: the two matvecs run concurrently ----
        if (frun) {
            f32x2 acc[4] = {{0.f,0.f},{0.f,0.f},{0.f,0.f},{0.f,0.f}};
            union_sum7(W1T, actF, fmpF, npad, htid, acc);
            const float accs[SPIKE_STEPS] =
                {acc[0].x, acc[0].y, acc[1].x, acc[1].y, acc[2].x, acc[2].y, acc[3].x};
            #pragma unroll
            for (int s = 0; s < SPIKE_STEPS; ++s) {
                bool reset1 = (mem1 - thr1) > 0.f;
                mem1 = reset1 ? 0.f : __fadd_rn(__fmul_rn(beta1, mem1), accs[s]);
                bool z1 = (mem1 - thr1) > 0.f;
                unsigned long long bal1 = __ballot(z1);
                if (hlane == 0) zr[it & 1][s][hwid] = bal1;
            }
        } else if (brun) {
            f32x2 acc[4] = {{0.f,0.f},{0.f,0.f},{0.f,0.f},{0.f,0.f}};
            union_sum7(W2T, actB, fmpB, npad, htid, acc);
            const float accs[SPIKE_STEPS] =
                {acc[0].x, acc[0].y, acc[1].x, acc[1].y, acc[2].x, acc[2].y, acc[3].x};
            float w0 = 0.f, w1 = 0.f;
            #pragma unroll
            for (int s = 0; s < SPIKE_STEPS; ++s) {
                bool reset2 = (mem2 - thr2) > 0.f;
                mem2 = reset2 ? 0.f : __fadd_rn(__fmul_rn(beta2, mem2), accs[s]);
                bool z2 = (mem2 - thr2) > 0.f;
                a0s += z2 ? wo0 : 0.f;
                a1s += z2 ? wo1 : 0.f;
                w0 += a0s;
                w1 += a1s;
            }
            // cross-thread reduction (within back half): wave shfl + red[]
            float r0 = w0, r1 = w1;
            #pragma unroll
            for (int off = 32; off > 0; off >>= 1) {
                r0 += __shfl_down(r0, off);
                r1 += __shfl_down(r1, off);
            }
            if (hlane == 0) { red[hwid * 2] = r0; red[hwid * 2 + 1] = r1; }
        }
        __syncthreads();                                   // B3

        // out-write for step it-1 (red[] valid until phase C of it+1)
        if (brun && htid == 0) {
            float s0 = 0.f, s1 = 0.f;
            #pragma unroll
            for (int q = 0; q < 8; ++q) { s0 += red[q * 2]; s1 += red[q * 2 + 1]; }
            out[((it - 1) * BATCH + b) * OUT_DIM + 0] = s0 / 7.0f;
            out[((it - 1) * BATCH + b) * OUT_DIM + 1] = s1 / 7.0f;
        }
    }
}

extern "C" void kernel_launch(void* const* d_in, const int* in_sizes, int n_in,
                              void* d_out, int out_size, void* d_ws, size_t ws_size,
                              hipStream_t stream) {
    const float* x     = (const float*)d_in[0];
    const float* W0    = (const float*)d_in[1];
    const float* W1    = (const float*)d_in[2];
    const float* W2    = (const float*)d_in[3];
    const float* Wout  = (const float*)d_in[4];
    const float* betas = (const float*)d_in[5];
    const float* thrs  = (const float*)d_in[6];
    float* out = (float*)d_out;

    float* ws  = (float*)d_ws;
    float* W0T = ws + W0T_OFF;
    float* W1T = ws + W1T_OFF;
    float* W2T = ws + W2T_OFF;

    {
        int n = HIDDEN * IN_DIM;
        transpose_kernel<<<(n + 255) / 256, 256, 0, stream>>>(W0, W0T, HIDDEN, IN_DIM);
    }
    {
        int n = HIDDEN * HIDDEN;
        transpose_kernel<<<(n + 255) / 256, 256, 0, stream>>>(W1, W1T, HIDDEN, HIDDEN);
        transpose_kernel<<<(n + 255) / 256, 256, 0, stream>>>(W2, W2T, HIDDEN, HIDDEN);
    }

    snn_merged_kernel<<<BATCH, 1024, 0, stream>>>(
        x, Wout, betas, thrs, W0T, W1T, W2T, out);
}

// Round 12
// 3624.858 us; speedup vs baseline: 1.1779x; 1.1779x over previous
//
#include <hip/hip_runtime.h>
#include <hip/hip_fp16.h>

#define SEQ_LEN 256
#define SPIKE_STEPS 7
#define BATCH 128
#define IN_DIM 96
#define HIDDEN 512
#define OUT_DIM 2

// d_ws layout (f32 weights):
//   W0T [96*512] | W1T [512*512] | W2T [512*512] | ctr | zbuf[B][256][56]u64
#define W0T_OFF 0
#define W1T_OFF (IN_DIM * HIDDEN)
#define W2T_OFF (W1T_OFF + HIDDEN * HIDDEN)
#define CTR_BYTE_OFF ((size_t)(W2T_OFF + HIDDEN * HIDDEN) * sizeof(float))
#define ZBUF_BYTE_OFF (CTR_BYTE_OFF + 1024)

typedef float f32x4 __attribute__((ext_vector_type(4)));
typedef float f32x2 __attribute__((ext_vector_type(2)));

__global__ void transpose_kernel(const float* __restrict__ in, float* __restrict__ out,
                                 int rows, int cols) {
    int idx = blockIdx.x * blockDim.x + threadIdx.x;
    if (idx < rows * cols) {
        int r = idx / cols, c = idx - r * cols;
        out[c * rows + r] = in[idx];
    }
}

// Packed f32 fma: acc.{lo,hi} += w * m.{lo,hi}. Lowers to v_pk_fma_f32
// (VOP3P) on gfx950 (proven R5/R7). Each half is an independent IEEE RN fma
// => bit-identical to two scalar __fmaf_rn. The two halves belong to
// DIFFERENT steps' accumulator chains => no reordering within any step.
__device__ __forceinline__ void pkfma(f32x2& acc, float w, f32x2 m) {
    const f32x2 wv = {w, w};
    acc = __builtin_elementwise_fma(wv, m, acc);
}

// u32 = 2 packed f16 mask values (each exactly 0.0h or 1.0h=0x3C00).
// v_cvt_f32_f16 of 0/1 is EXACT => downstream fma bit-identical to f32 masks.
__device__ __forceinline__ f32x2 cvt2(unsigned u) {
    __half2 h = *reinterpret_cast<__half2*>(&u);
    float2 f = __half22float2(h);
    f32x2 r = {f.x, f.y};
    return r;
}

// Union-batched 7-step row sum (R7 depth-1 pipeline) with f16 masks.
// R5/R7/R8/R10 triangulate the bottleneck to the CU's LDS broadcast-return
// path (~8 cyc per wave-uniform ds_read_b128, shared across the CU's waves).
// f16 masks halve the dominant term: ONE b128 mask read per row (16B = 8
// f16) instead of two. Per 16-row group: 4 act + 16 mask b128 (was 4+32).
// Numerics: mask values are exactly {0h,1h}; cvt to f32 is exact; per step
// s the sum visits union rows in ascending rank order; active rows add
// fma(1,w,acc)=RN(acc+w); inactive rows add fma(0,w,acc)=acc exactly (acc
// never -0: starts +0, +0 + +/-0 = +0 in RN). Pads are (row 0, mask 0).
// => bit-identical to R1/R3/R7 (absmax must be exactly 0.25).
__device__ __forceinline__ void union_sum7(const float* __restrict__ W,
                                           const int* __restrict__ act,
                                           const uint4* __restrict__ fmp,
                                           int npad, int col,
                                           f32x2* __restrict__ acc) {
    if (npad <= 0) return;
    const float* Wt = W + col;
    int rows[16];
    float wc[16];
    {
        const int4* av = reinterpret_cast<const int4*>(act);
        int4 a0 = av[0], a1 = av[1], a2 = av[2], a3 = av[3];
        rows[0]=a0.x; rows[1]=a0.y; rows[2]=a0.z; rows[3]=a0.w;
        rows[4]=a1.x; rows[5]=a1.y; rows[6]=a1.z; rows[7]=a1.w;
        rows[8]=a2.x; rows[9]=a2.y; rows[10]=a2.z; rows[11]=a2.w;
        rows[12]=a3.x; rows[13]=a3.y; rows[14]=a3.z; rows[15]=a3.w;
    }
    #pragma unroll
    for (int k = 0; k < 16; ++k) wc[k] = Wt[rows[k] * HIDDEN];

    for (int n = 16; n < npad; n += 16) {
        int nrows[16];
        float wn[16];
        {
            const int4* av = reinterpret_cast<const int4*>(act + n);
            int4 a0 = av[0], a1 = av[1], a2 = av[2], a3 = av[3];
            nrows[0]=a0.x; nrows[1]=a0.y; nrows[2]=a0.z; nrows[3]=a0.w;
            nrows[4]=a1.x; nrows[5]=a1.y; nrows[6]=a1.z; nrows[7]=a1.w;
            nrows[8]=a2.x; nrows[9]=a2.y; nrows[10]=a2.z; nrows[11]=a2.w;
            nrows[12]=a3.x; nrows[13]=a3.y; nrows[14]=a3.z; nrows[15]=a3.w;
        }
        #pragma unroll
        for (int k = 0; k < 16; ++k) wn[k] = Wt[nrows[k] * HIDDEN];

        const int base = n - 16;
        #pragma unroll
        for (int k = 0; k < 16; ++k) {
            uint4 mv = fmp[base + k];
            pkfma(acc[0], wc[k], cvt2(mv.x));
            pkfma(acc[1], wc[k], cvt2(mv.y));
            pkfma(acc[2], wc[k], cvt2(mv.z));
            pkfma(acc[3], wc[k], cvt2(mv.w));
        }
        #pragma unroll
        for (int k = 0; k < 16; ++k) wc[k] = wn[k];
    }
    const int base = npad - 16;
    #pragma unroll
    for (int k = 0; k < 16; ++k) {
        uint4 mv = fmp[base + k];
        pkfma(acc[0], wc[k], cvt2(mv.x));
        pkfma(acc[1], wc[k], cvt2(mv.y));
        pkfma(acc[2], wc[k], cvt2(mv.z));
        pkfma(acc[3], wc[k], cvt2(mv.w));
    }
}

// Build the union active list (ascending neuron order) + rank-indexed
// packed-f16 per-row step masks. m7 = this thread's 7 firing bits.
__device__ __forceinline__ int build_union(const unsigned long long (*zm7)[8],
                                           int* act, uint4* fmp,
                                           int wid, int lane, int tid, int m7) {
    unsigned long long um[8];
    #pragma unroll
    for (int q = 0; q < 8; ++q) {
        unsigned long long u = zm7[0][q];
        #pragma unroll
        for (int s = 1; s < SPIKE_STEPS; ++s) u |= zm7[s][q];
        um[q] = u;
    }
    int pre = 0, total = 0;
    #pragma unroll
    for (int q = 0; q < 8; ++q) {
        int p = __popcll(um[q]);
        total += p;
        if (q < wid) pre += p;
    }
    if (m7 != 0) {
        int rank = pre + __popcll(um[wid] & ((1ull << lane) - 1ull));
        act[rank] = tid;
        // pack 7 masks as f16 pairs: 1.0h = 0x3C00 in lo/hi halves of u32
        uint4 v;
        v.x = ((m7 & 1)  ? 0x3C00u : 0u) | ((m7 & 2)  ? 0x3C000000u : 0u);
        v.y = ((m7 & 4)  ? 0x3C00u : 0u) | ((m7 & 8)  ? 0x3C000000u : 0u);
        v.z = ((m7 & 16) ? 0x3C00u : 0u) | ((m7 & 32) ? 0x3C000000u : 0u);
        v.w = ((m7 & 64) ? 0x3C00u : 0u);
        fmp[rank] = v;
    }
    int npad = (total + 15) & ~15;
    if (tid < npad - total) {
        act[total + tid] = 0;                          // row 0, mask 0 pad
        const uint4 z = {0u, 0u, 0u, 0u};
        fmp[total + tid] = z;
    }
    return npad;
}

// Two-stage pipeline: even blocks = producer (layer0+layer1), odd = consumer
// (layer2+output). Handoff granularity = one seq step (7 masks at once).
// 3 barriers per seq step per role (xs double-buffered; spin+load merged).
__launch_bounds__(512, 1)
__global__ void snn_pipe_kernel(const float* __restrict__ x,     // [256,128,96]
                                const float* __restrict__ Wout,  // [2,512]
                                const float* __restrict__ betas, // [3]
                                const float* __restrict__ thrs,  // [3]
                                const float* __restrict__ W0T,   // [96,512]
                                const float* __restrict__ W1T,   // [512,512]
                                const float* __restrict__ W2T,   // [512,512]
                                unsigned long long* __restrict__ zbuf,
                                int* __restrict__ ctr,
                                float* __restrict__ out)         // [256,128,2]
{
    const int b    = blockIdx.x >> 1;
    const int role = blockIdx.x & 1;
    const int tid  = threadIdx.x;
    const int lane = tid & 63;
    const int wid  = tid >> 6;

    __shared__ float xs[2][IN_DIM];
    __shared__ unsigned long long zm7[SPIKE_STEPS][8];
    __shared__ int act[HIDDEN];
    __shared__ __align__(16) uint4 fmp[HIDDEN];      // 8 KB packed f16 masks
    __shared__ float red[16];

    if (role == 0) {
        // ---------------- producer: layer0 + layer1 ----------------
        const float beta0 = betas[0], beta1 = betas[1];
        const float thr0  = thrs[0],  thr1  = thrs[1];
        float mem0 = 0.f, mem1 = 0.f;
        unsigned long long* zb = zbuf + (size_t)b * SEQ_LEN * 56;

        if (tid < IN_DIM) xs[0][tid] = x[(0 * BATCH + b) * IN_DIM + tid];
        __syncthreads();                                        // prologue

        for (int i = 0; i < SEQ_LEN; ++i) {
            const int cur = i & 1;

            float cur0 = 0.f;
            #pragma unroll 8
            for (int k = 0; k < IN_DIM; ++k)
                cur0 = __fmaf_rn(xs[cur][k], W0T[k * HIDDEN + tid], cur0);

            // prefetch next step's x slice into the other xs buffer
            if (i + 1 < SEQ_LEN && tid < IN_DIM)
                xs[cur ^ 1][tid] = x[((i + 1) * BATCH + b) * IN_DIM + tid];

            // layer-0 recurrence is autonomous within the seq step:
            // compute all 7 z0 masks upfront.
            int m7 = 0;
            #pragma unroll
            for (int s = 0; s < SPIKE_STEPS; ++s) {
                bool reset0 = (mem0 - thr0) > 0.f;
                mem0 = reset0 ? 0.f : __fadd_rn(__fmul_rn(beta0, mem0), cur0);
                bool z0 = (mem0 - thr0) > 0.f;
                m7 |= (int)z0 << s;
                unsigned long long bal = __ballot(z0);
                if (lane == 0) zm7[s][wid] = bal;
            }
            __syncthreads();                                    // B1: zm7 ready

            int npad = build_union(zm7, act, fmp, wid, lane, tid, m7);
            __syncthreads();                                    // B2: act/fmp ready

            f32x2 acc[4] = {{0.f,0.f},{0.f,0.f},{0.f,0.f},{0.f,0.f}};
            union_sum7(W1T, act, fmp, npad, tid, acc);
            const float accs[SPIKE_STEPS] =
                {acc[0].x, acc[0].y, acc[1].x, acc[1].y, acc[2].x, acc[2].y, acc[3].x};

            // layer-1 recurrence over the 7 steps, emit z1 masks
            #pragma unroll
            for (int s = 0; s < SPIKE_STEPS; ++s) {
                bool reset1 = (mem1 - thr1) > 0.f;
                mem1 = reset1 ? 0.f : __fadd_rn(__fmul_rn(beta1, mem1), accs[s]);
                bool z1 = (mem1 - thr1) > 0.f;
                unsigned long long bal1 = __ballot(z1);
                if (lane == 0)
                    __hip_atomic_store(&zb[(size_t)i * 56 + s * 8 + wid], bal1,
                                       __ATOMIC_RELAXED, __HIP_MEMORY_SCOPE_AGENT);
            }
            __syncthreads();   // B3: all waves' mask stores drained (vmcnt 0)
            if (tid == 0)
                __hip_atomic_store(&ctr[b], i + 1,
                                   __ATOMIC_RELAXED, __HIP_MEMORY_SCOPE_AGENT);
        }
    } else {
        // ---------------- consumer: layer2 + output ----------------
        const float beta2 = betas[2];
        const float thr2  = thrs[2];
        const float wo0 = Wout[tid];
        const float wo1 = Wout[HIDDEN + tid];
        float mem2 = 0.f;
        // Deferred output reduction: per-thread integrator a, prefix
        // accumulator w; one cross-thread reduction per seq step.
        float a0s = 0.f, a1s = 0.f;
        const unsigned long long* zb = zbuf + (size_t)b * SEQ_LEN * 56;

        for (int i = 0; i < SEQ_LEN; ++i) {
            // merged spin + mask load: the 56 loader threads (wave 0) spin on
            // the same ctr cacheline, then fetch the masks; one barrier total.
            if (tid < 56) {
                while (__hip_atomic_load(&ctr[b], __ATOMIC_RELAXED,
                                         __HIP_MEMORY_SCOPE_AGENT) < i + 1)
                    __builtin_amdgcn_s_sleep(1);
                ((unsigned long long*)zm7)[tid] =
                    __hip_atomic_load(&zb[(size_t)i * 56 + tid],
                                      __ATOMIC_RELAXED, __HIP_MEMORY_SCOPE_AGENT);
            }
            __syncthreads();                                    // B1: zm7 ready

            int m7 = 0;
            #pragma unroll
            for (int s = 0; s < SPIKE_STEPS; ++s)
                m7 |= (int)((zm7[s][wid] >> lane) & 1ull) << s;

            int npad = build_union(zm7, act, fmp, wid, lane, tid, m7);
            __syncthreads();                                    // B2: act/fmp ready

            f32x2 acc[4] = {{0.f,0.f},{0.f,0.f},{0.f,0.f},{0.f,0.f}};
            union_sum7(W2T, act, fmp, npad, tid, acc);
            const float accs[SPIKE_STEPS] =
                {acc[0].x, acc[0].y, acc[1].x, acc[1].y, acc[2].x, acc[2].y, acc[3].x};

            float w0 = 0.f, w1 = 0.f;
            #pragma unroll
            for (int s = 0; s < SPIKE_STEPS; ++s) {
                bool reset2 = (mem2 - thr2) > 0.f;
                mem2 = reset2 ? 0.f : __fadd_rn(__fmul_rn(beta2, mem2), accs[s]);
                bool z2 = (mem2 - thr2) > 0.f;
                a0s += z2 ? wo0 : 0.f;
                a1s += z2 ? wo1 : 0.f;
                w0 += a0s;
                w1 += a1s;
            }

            // one cross-thread reduction per seq step
            float r0 = w0, r1 = w1;
            #pragma unroll
            for (int off = 32; off > 0; off >>= 1) {
                r0 += __shfl_down(r0, off);
                r1 += __shfl_down(r1, off);
            }
            if (lane == 0) { red[wid * 2] = r0; red[wid * 2 + 1] = r1; }
            __syncthreads();                                    // B3
            if (tid == 0) {
                float s0 = 0.f, s1 = 0.f;
                #pragma unroll
                for (int q = 0; q < 8; ++q) { s0 += red[q * 2]; s1 += red[q * 2 + 1]; }
                out[(i * BATCH + b) * OUT_DIM + 0] = s0 / 7.0f;
                out[(i * BATCH + b) * OUT_DIM + 1] = s1 / 7.0f;
            }
            // next write to red is a full seq step away (>=2 barriers) and
            // tid0's read precedes its next barrier => no extra barrier.
        }
    }
}

extern "C" void kernel_launch(void* const* d_in, const int* in_sizes, int n_in,
                              void* d_out, int out_size, void* d_ws, size_t ws_size,
                              hipStream_t stream) {
    const float* x     = (const float*)d_in[0];
    const float* W0    = (const float*)d_in[1];
    const float* W1    = (const float*)d_in[2];
    const float* W2    = (const float*)d_in[3];
    const float* Wout  = (const float*)d_in[4];
    const float* betas = (const float*)d_in[5];
    const float* thrs  = (const float*)d_in[6];
    float* out = (float*)d_out;

    float* ws  = (float*)d_ws;
    float* W0T = ws + W0T_OFF;
    float* W1T = ws + W1T_OFF;
    float* W2T = ws + W2T_OFF;
    int* ctr = (int*)((char*)d_ws + CTR_BYTE_OFF);
    unsigned long long* zbuf = (unsigned long long*)((char*)d_ws + ZBUF_BYTE_OFF);

    {
        int n = HIDDEN * IN_DIM;
        transpose_kernel<<<(n + 255) / 256, 256, 0, stream>>>(W0, W0T, HIDDEN, IN_DIM);
    }
    {
        int n = HIDDEN * HIDDEN;
        transpose_kernel<<<(n + 255) / 256, 256, 0, stream>>>(W1, W1T, HIDDEN, HIDDEN);
        transpose_kernel<<<(n + 255) / 256, 256, 0, stream>>>(W2, W2T, HIDDEN, HIDDEN);
    }

    hipMemsetAsync((char*)d_ws + CTR_BYTE_OFF, 0, 1024, stream);

    snn_pipe_kernel<<<2 * BATCH, HIDDEN, 0, stream>>>(
        x, Wout, betas, thrs, W0T, W1T, W2T, zbuf, ctr, out);
}

// Round 13
// 2927.352 us; speedup vs baseline: 1.4585x; 1.2383x over previous
//
#include <hip/hip_runtime.h>

#define SEQ_LEN 256
#define SPIKE_STEPS 7
#define BATCH 128
#define IN_DIM 96
#define HIDDEN 512
#define OUT_DIM 2

// d_ws layout (f32 weights):
//   W0T [96*512] | W1T [512*512] | W2T [512*512] | ctr | zbuf[B][256][56]u64
#define W0T_OFF 0
#define W1T_OFF (IN_DIM * HIDDEN)
#define W2T_OFF (W1T_OFF + HIDDEN * HIDDEN)
#define CTR_BYTE_OFF ((size_t)(W2T_OFF + HIDDEN * HIDDEN) * sizeof(float))
#define ZBUF_BYTE_OFF (CTR_BYTE_OFF + 1024)

typedef float f32x4 __attribute__((ext_vector_type(4)));
typedef float f32x2 __attribute__((ext_vector_type(2)));

__global__ void transpose_kernel(const float* __restrict__ in, float* __restrict__ out,
                                 int rows, int cols) {
    int idx = blockIdx.x * blockDim.x + threadIdx.x;
    if (idx < rows * cols) {
        int r = idx / cols, c = idx - r * cols;
        out[c * rows + r] = in[idx];
    }
}

// Packed f32 fma: acc.{lo,hi} += w * m.{lo,hi}. Lowers to v_pk_fma_f32
// (VOP3P) on gfx950 (proven R5/R7). Each half is an independent IEEE RN fma
// => bit-identical to two scalar __fmaf_rn. The two halves belong to
// DIFFERENT steps' accumulator chains => no reordering within any step.
__device__ __forceinline__ void pkfma(f32x2& acc, float w, f32x2 m) {
    const f32x2 wv = {w, w};
    acc = __builtin_elementwise_fma(wv, m, acc);
}

// TWO-COLUMN union-batched 7-step row sum (R7 depth-1 pipeline).
// The session's measurements (R5/R7/R10/R12) fit one model: the CU's LDS
// broadcast-return path costs ~8 cyc per wave-uniform ds_read_b128 and is
// consumed INDEPENDENTLY by every wave reading the shared act/fmp stream.
// Fix: only waves 0-3 run this phase, each thread covering columns tid and
// tid+256 => the broadcast stream is read by 4 waves instead of 8 (LDS
// cycles halved), while the mask read cost per row per wave is unchanged.
// Numerics: per column, per step s, union rows visited in ascending rank
// order; active rows add fma(1,w,acc)=RN(acc+w); inactive rows add
// fma(0,w,acc)=acc exactly (acc never -0: starts +0, +0 + +/-0 = +0 in RN).
// Pads are (row 0, mask 0). => per-column sums bit-identical to R1/R3/R7
// (absmax must be exactly 0.25).
__device__ __forceinline__ void union_sum7_2(const float* __restrict__ W,
                                             const int* __restrict__ act,
                                             const float (* __restrict__ fmp)[8],
                                             int npad, int tid,
                                             f32x2* __restrict__ accA,
                                             f32x2* __restrict__ accB) {
    if (npad <= 0) return;
    const float* WtA = W + tid;
    const float* WtB = W + tid + 256;
    int rows[16];
    float wcA[16], wcB[16];
    {
        const int4* av = reinterpret_cast<const int4*>(act);
        int4 a0 = av[0], a1 = av[1], a2 = av[2], a3 = av[3];
        rows[0]=a0.x; rows[1]=a0.y; rows[2]=a0.z; rows[3]=a0.w;
        rows[4]=a1.x; rows[5]=a1.y; rows[6]=a1.z; rows[7]=a1.w;
        rows[8]=a2.x; rows[9]=a2.y; rows[10]=a2.z; rows[11]=a2.w;
        rows[12]=a3.x; rows[13]=a3.y; rows[14]=a3.z; rows[15]=a3.w;
    }
    #pragma unroll
    for (int k = 0; k < 16; ++k) {
        wcA[k] = WtA[rows[k] * HIDDEN];
        wcB[k] = WtB[rows[k] * HIDDEN];
    }

    for (int n = 16; n < npad; n += 16) {
        int nrows[16];
        float wnA[16], wnB[16];
        {
            const int4* av = reinterpret_cast<const int4*>(act + n);
            int4 a0 = av[0], a1 = av[1], a2 = av[2], a3 = av[3];
            nrows[0]=a0.x; nrows[1]=a0.y; nrows[2]=a0.z; nrows[3]=a0.w;
            nrows[4]=a1.x; nrows[5]=a1.y; nrows[6]=a1.z; nrows[7]=a1.w;
            nrows[8]=a2.x; nrows[9]=a2.y; nrows[10]=a2.z; nrows[11]=a2.w;
            nrows[12]=a3.x; nrows[13]=a3.y; nrows[14]=a3.z; nrows[15]=a3.w;
        }
        #pragma unroll
        for (int k = 0; k < 16; ++k) {
            wnA[k] = WtA[nrows[k] * HIDDEN];
            wnB[k] = WtB[nrows[k] * HIDDEN];
        }

        const int base = n - 16;
        #pragma unroll
        for (int k = 0; k < 16; ++k) {
            f32x4 fa = *reinterpret_cast<const f32x4*>(&fmp[base + k][0]);
            f32x4 fb = *reinterpret_cast<const f32x4*>(&fmp[base + k][4]);
            f32x2 m01 = __builtin_shufflevector(fa, fa, 0, 1);
            f32x2 m23 = __builtin_shufflevector(fa, fa, 2, 3);
            f32x2 m45 = __builtin_shufflevector(fb, fb, 0, 1);
            f32x2 m67 = __builtin_shufflevector(fb, fb, 2, 3);
            pkfma(accA[0], wcA[k], m01);
            pkfma(accA[1], wcA[k], m23);
            pkfma(accA[2], wcA[k], m45);
            pkfma(accA[3], wcA[k], m67);
            pkfma(accB[0], wcB[k], m01);
            pkfma(accB[1], wcB[k], m23);
            pkfma(accB[2], wcB[k], m45);
            pkfma(accB[3], wcB[k], m67);
        }
        #pragma unroll
        for (int k = 0; k < 16; ++k) { wcA[k] = wnA[k]; wcB[k] = wnB[k]; }
    }
    const int base = npad - 16;
    #pragma unroll
    for (int k = 0; k < 16; ++k) {
        f32x4 fa = *reinterpret_cast<const f32x4*>(&fmp[base + k][0]);
        f32x4 fb = *reinterpret_cast<const f32x4*>(&fmp[base + k][4]);
        f32x2 m01 = __builtin_shufflevector(fa, fa, 0, 1);
        f32x2 m23 = __builtin_shufflevector(fa, fa, 2, 3);
        f32x2 m45 = __builtin_shufflevector(fb, fb, 0, 1);
        f32x2 m67 = __builtin_shufflevector(fb, fb, 2, 3);
        pkfma(accA[0], wcA[k], m01);
        pkfma(accA[1], wcA[k], m23);
        pkfma(accA[2], wcA[k], m45);
        pkfma(accA[3], wcA[k], m67);
        pkfma(accB[0], wcB[k], m01);
        pkfma(accB[1], wcB[k], m23);
        pkfma(accB[2], wcB[k], m45);
        pkfma(accB[3], wcB[k], m67);
    }
}

// Build the union active list (ascending neuron order) + rank-indexed
// per-row step-mask floats. Full 512-thread phase (unchanged from R7).
__device__ __forceinline__ int build_union(const unsigned long long (*zm7)[8],
                                           int* act, float (*fmp)[8],
                                           int wid, int lane, int tid, int m7) {
    unsigned long long um[8];
    #pragma unroll
    for (int q = 0; q < 8; ++q) {
        unsigned long long u = zm7[0][q];
        #pragma unroll
        for (int s = 1; s < SPIKE_STEPS; ++s) u |= zm7[s][q];
        um[q] = u;
    }
    int pre = 0, total = 0;
    #pragma unroll
    for (int q = 0; q < 8; ++q) {
        int p = __popcll(um[q]);
        total += p;
        if (q < wid) pre += p;
    }
    if (m7 != 0) {
        int rank = pre + __popcll(um[wid] & ((1ull << lane) - 1ull));
        act[rank] = tid;
        f32x4 v0, v4;
        #pragma unroll
        for (int s = 0; s < 4; ++s) v0[s] = ((m7 >> s) & 1) ? 1.0f : 0.0f;
        #pragma unroll
        for (int s = 0; s < 3; ++s) v4[s] = ((m7 >> (4 + s)) & 1) ? 1.0f : 0.0f;
        v4[3] = 0.f;
        *reinterpret_cast<f32x4*>(&fmp[rank][0]) = v0;
        *reinterpret_cast<f32x4*>(&fmp[rank][4]) = v4;
    }
    int npad = (total + 15) & ~15;
    if (tid < npad - total) {
        act[total + tid] = 0;                          // row 0, mask 0 pad
        const f32x4 z = {0.f, 0.f, 0.f, 0.f};
        *reinterpret_cast<f32x4*>(&fmp[total + tid][0]) = z;
        *reinterpret_cast<f32x4*>(&fmp[total + tid][4]) = z;
    }
    return npad;
}

// Two-stage pipeline: even blocks = producer (layer0+layer1), odd = consumer
// (layer2+output). Handoff granularity = one seq step (7 masks at once).
// Cheap phases (layer0, ballots, build) run 512-wide; the LDS-heavy matvec
// + recurrence runs on waves 0-3 only (2 cols/thread) — waves 4-7 idle at
// the barrier so the broadcast act/fmp stream has 4 readers, not 8.
__launch_bounds__(512, 1)
__global__ void snn_pipe_kernel(const float* __restrict__ x,     // [256,128,96]
                                const float* __restrict__ Wout,  // [2,512]
                                const float* __restrict__ betas, // [3]
                                const float* __restrict__ thrs,  // [3]
                                const float* __restrict__ W0T,   // [96,512]
                                const float* __restrict__ W1T,   // [512,512]
                                const float* __restrict__ W2T,   // [512,512]
                                unsigned long long* __restrict__ zbuf,
                                int* __restrict__ ctr,
                                float* __restrict__ out)         // [256,128,2]
{
    const int b    = blockIdx.x >> 1;
    const int role = blockIdx.x & 1;
    const int tid  = threadIdx.x;
    const int lane = tid & 63;
    const int wid  = tid >> 6;
    const bool mv  = (tid < 256);       // matvec-active threads (waves 0-3)

    __shared__ float xs[2][IN_DIM];
    __shared__ unsigned long long zm7[SPIKE_STEPS][8];
    __shared__ int act[HIDDEN];
    __shared__ __align__(16) float fmp[HIDDEN][8];   // rank-indexed masks
    __shared__ float red[8];

    if (role == 0) {
        // ---------------- producer: layer0 + layer1 ----------------
        const float beta0 = betas[0], beta1 = betas[1];
        const float thr0  = thrs[0],  thr1  = thrs[1];
        float mem0 = 0.f;                       // 512-layout: neuron tid
        float mem1A = 0.f, mem1B = 0.f;         // 2-col layout: tid, tid+256
        unsigned long long* zb = zbuf + (size_t)b * SEQ_LEN * 56;

        if (tid < IN_DIM) xs[0][tid] = x[(0 * BATCH + b) * IN_DIM + tid];
        __syncthreads();                                        // prologue

        for (int i = 0; i < SEQ_LEN; ++i) {
            const int cur = i & 1;

            float cur0 = 0.f;
            #pragma unroll 8
            for (int k = 0; k < IN_DIM; ++k)
                cur0 = __fmaf_rn(xs[cur][k], W0T[k * HIDDEN + tid], cur0);

            // prefetch next step's x slice into the other xs buffer
            if (i + 1 < SEQ_LEN && tid < IN_DIM)
                xs[cur ^ 1][tid] = x[((i + 1) * BATCH + b) * IN_DIM + tid];

            // layer-0 recurrence (autonomous within the seq step), 512-wide
            int m7 = 0;
            #pragma unroll
            for (int s = 0; s < SPIKE_STEPS; ++s) {
                bool reset0 = (mem0 - thr0) > 0.f;
                mem0 = reset0 ? 0.f : __fadd_rn(__fmul_rn(beta0, mem0), cur0);
                bool z0 = (mem0 - thr0) > 0.f;
                m7 |= (int)z0 << s;
                unsigned long long bal = __ballot(z0);
                if (lane == 0) zm7[s][wid] = bal;
            }
            __syncthreads();                                    // B1: zm7 ready

            int npad = build_union(zm7, act, fmp, wid, lane, tid, m7);
            __syncthreads();                                    // B2: act/fmp ready

            if (mv) {
                f32x2 accA[4] = {{0.f,0.f},{0.f,0.f},{0.f,0.f},{0.f,0.f}};
                f32x2 accB[4] = {{0.f,0.f},{0.f,0.f},{0.f,0.f},{0.f,0.f}};
                union_sum7_2(W1T, act, fmp, npad, tid, accA, accB);
                const float accsA[SPIKE_STEPS] =
                    {accA[0].x, accA[0].y, accA[1].x, accA[1].y, accA[2].x, accA[2].y, accA[3].x};
                const float accsB[SPIKE_STEPS] =
                    {accB[0].x, accB[0].y, accB[1].x, accB[1].y, accB[2].x, accB[2].y, accB[3].x};

                // layer-1 recurrence for both columns, emit z1 ballots.
                // neuron n bit lives at qword n>>6, bit n&63 (unchanged).
                #pragma unroll
                for (int s = 0; s < SPIKE_STEPS; ++s) {
                    bool r1A = (mem1A - thr1) > 0.f;
                    mem1A = r1A ? 0.f : __fadd_rn(__fmul_rn(beta1, mem1A), accsA[s]);
                    bool z1A = (mem1A - thr1) > 0.f;
                    bool r1B = (mem1B - thr1) > 0.f;
                    mem1B = r1B ? 0.f : __fadd_rn(__fmul_rn(beta1, mem1B), accsB[s]);
                    bool z1B = (mem1B - thr1) > 0.f;
                    unsigned long long balA = __ballot(z1A);
                    unsigned long long balB = __ballot(z1B);
                    if (lane == 0) {
                        __hip_atomic_store(&zb[(size_t)i * 56 + s * 8 + wid], balA,
                                           __ATOMIC_RELAXED, __HIP_MEMORY_SCOPE_AGENT);
                        __hip_atomic_store(&zb[(size_t)i * 56 + s * 8 + 4 + wid], balB,
                                           __ATOMIC_RELAXED, __HIP_MEMORY_SCOPE_AGENT);
                    }
                }
            }
            __syncthreads();   // B3: all waves' mask stores drained (vmcnt 0)
            if (tid == 0)
                __hip_atomic_store(&ctr[b], i + 1,
                                   __ATOMIC_RELAXED, __HIP_MEMORY_SCOPE_AGENT);
        }
    } else {
        // ---------------- consumer: layer2 + output ----------------
        const float beta2 = betas[2];
        const float thr2  = thrs[2];
        // 2-col output weights (only meaningful for tid<256)
        const int cB = (tid & 255) + 256;
        const float wo0A = Wout[tid & 255];
        const float wo0B = Wout[cB];
        const float wo1A = Wout[HIDDEN + (tid & 255)];
        const float wo1B = Wout[HIDDEN + cB];
        float mem2A = 0.f, mem2B = 0.f;
        float a0s = 0.f, a1s = 0.f;            // combined over both columns
        const unsigned long long* zb = zbuf + (size_t)b * SEQ_LEN * 56;

        for (int i = 0; i < SEQ_LEN; ++i) {
            // merged spin + mask load (wave 0 only), one barrier total.
            if (tid < 56) {
                while (__hip_atomic_load(&ctr[b], __ATOMIC_RELAXED,
                                         __HIP_MEMORY_SCOPE_AGENT) < i + 1)
                    __builtin_amdgcn_s_sleep(1);
                ((unsigned long long*)zm7)[tid] =
                    __hip_atomic_load(&zb[(size_t)i * 56 + tid],
                                      __ATOMIC_RELAXED, __HIP_MEMORY_SCOPE_AGENT);
            }
            __syncthreads();                                    // B1: zm7 ready

            // per-neuron m7 (512-wide layout: neuron tid)
            int m7 = 0;
            #pragma unroll
            for (int s = 0; s < SPIKE_STEPS; ++s)
                m7 |= (int)((zm7[s][wid] >> lane) & 1ull) << s;

            int npad = build_union(zm7, act, fmp, wid, lane, tid, m7);
            __syncthreads();                                    // B2: act/fmp ready

            if (mv) {
                f32x2 accA[4] = {{0.f,0.f},{0.f,0.f},{0.f,0.f},{0.f,0.f}};
                f32x2 accB[4] = {{0.f,0.f},{0.f,0.f},{0.f,0.f},{0.f,0.f}};
                union_sum7_2(W2T, act, fmp, npad, tid, accA, accB);
                const float accsA[SPIKE_STEPS] =
                    {accA[0].x, accA[0].y, accA[1].x, accA[1].y, accA[2].x, accA[2].y, accA[3].x};
                const float accsB[SPIKE_STEPS] =
                    {accB[0].x, accB[0].y, accB[1].x, accB[1].y, accB[2].x, accB[2].y, accB[3].x};

                float w0 = 0.f, w1 = 0.f;
                #pragma unroll
                for (int s = 0; s < SPIKE_STEPS; ++s) {
                    bool r2A = (mem2A - thr2) > 0.f;
                    mem2A = r2A ? 0.f : __fadd_rn(__fmul_rn(beta2, mem2A), accsA[s]);
                    bool z2A = (mem2A - thr2) > 0.f;
                    bool r2B = (mem2B - thr2) > 0.f;
                    mem2B = r2B ? 0.f : __fadd_rn(__fmul_rn(beta2, mem2B), accsB[s]);
                    bool z2B = (mem2B - thr2) > 0.f;
                    a0s += z2A ? wo0A : 0.f;
                    a0s += z2B ? wo0B : 0.f;
                    a1s += z2A ? wo1A : 0.f;
                    a1s += z2B ? wo1B : 0.f;
                    w0 += a0s;
                    w1 += a1s;
                }

                // cross-thread reduction over the 4 active waves
                float r0 = w0, r1 = w1;
                #pragma unroll
                for (int off = 32; off > 0; off >>= 1) {
                    r0 += __shfl_down(r0, off);
                    r1 += __shfl_down(r1, off);
                }
                if (lane == 0) { red[wid * 2] = r0; red[wid * 2 + 1] = r1; }
            }
            __syncthreads();                                    // B3
            if (tid == 0) {
                float s0 = 0.f, s1 = 0.f;
                #pragma unroll
                for (int q = 0; q < 4; ++q) { s0 += red[q * 2]; s1 += red[q * 2 + 1]; }
                out[(i * BATCH + b) * OUT_DIM + 0] = s0 / 7.0f;
                out[(i * BATCH + b) * OUT_DIM + 1] = s1 / 7.0f;
            }
            // next write to red is a full seq step away (>=2 barriers) and
            // tid0's read precedes its next barrier => no extra barrier.
        }
    }
}

extern "C" void kernel_launch(void* const* d_in, const int* in_sizes, int n_in,
                              void* d_out, int out_size, void* d_ws, size_t ws_size,
                              hipStream_t stream) {
    const float* x     = (const float*)d_in[0];
    const float* W0    = (const float*)d_in[1];
    const float* W1    = (const float*)d_in[2];
    const float* W2    = (const float*)d_in[3];
    const float* Wout  = (const float*)d_in[4];
    const float* betas = (const float*)d_in[5];
    const float* thrs  = (const float*)d_in[6];
    float* out = (float*)d_out;

    float* ws  = (float*)d_ws;
    float* W0T = ws + W0T_OFF;
    float* W1T = ws + W1T_OFF;
    float* W2T = ws + W2T_OFF;
    int* ctr = (int*)((char*)d_ws + CTR_BYTE_OFF);
    unsigned long long* zbuf = (unsigned long long*)((char*)d_ws + ZBUF_BYTE_OFF);

    {
        int n = HIDDEN * IN_DIM;
        transpose_kernel<<<(n + 255) / 256, 256, 0, stream>>>(W0, W0T, HIDDEN, IN_DIM);
    }
    {
        int n = HIDDEN * HIDDEN;
        transpose_kernel<<<(n + 255) / 256, 256, 0, stream>>>(W1, W1T, HIDDEN, HIDDEN);
        transpose_kernel<<<(n + 255) / 256, 256, 0, stream>>>(W2, W2T, HIDDEN, HIDDEN);
    }

    hipMemsetAsync((char*)d_ws + CTR_BYTE_OFF, 0, 1024, stream);

    snn_pipe_kernel<<<2 * BATCH, HIDDEN, 0, stream>>>(
        x, Wout, betas, thrs, W0T, W1T, W2T, zbuf, ctr, out);
}